// Round 2
// baseline (1185.264 us; speedup 1.0000x reference)
//
#include <hip/hip_runtime.h>
#include <math.h>

#define NN 100000
#define NE 3200000

constexpr int BLK = 256;
constexpr int GRID_EDGE = 2048;

typedef float f4 __attribute__((ext_vector_type(4)));
typedef _Float16 h4 __attribute__((ext_vector_type(4)));
typedef _Float16 h8 __attribute__((ext_vector_type(8)));

// ws layout (bytes):
//   [0,128)        stats: sum[16], sumsq[16]   (zeroed by node_proj block 0)
//   [1024, +3.2MB) p1h : NN rows x 16 half (32B/row)
//   [...,  +3.2MB) p2h
//   [..., +102.4MB) eh : NE rows x 16 half    (optional, if ws is big enough)

__device__ __forceinline__ void matvec16_acc(const float* __restrict__ sW,
                                             const float v[16], float acc[16]) {
  // acc[j] += sum_k v[k] * W[j][k]   (W row-major 16x16 in LDS, wave-uniform reads)
#pragma unroll
  for (int j = 0; j < 16; ++j) {
    float a = acc[j];
#pragma unroll
    for (int q = 0; q < 4; ++q) {
      float4 w = ((const float4*)(sW + j * 16))[q];
      a = fmaf(v[q * 4 + 0], w.x, a);
      a = fmaf(v[q * 4 + 1], w.y, a);
      a = fmaf(v[q * 4 + 2], w.z, a);
      a = fmaf(v[q * 4 + 3], w.w, a);
    }
    acc[j] = a;
  }
}

__device__ __forceinline__ void load_row16(const float* __restrict__ base,
                                           size_t row, float v[16]) {
  const f4* r = (const f4*)(base + row * 16);
#pragma unroll
  for (int q = 0; q < 4; ++q) {
    f4 t = r[q];
    v[q * 4 + 0] = t[0]; v[q * 4 + 1] = t[1];
    v[q * 4 + 2] = t[2]; v[q * 4 + 3] = t[3];
  }
}

__device__ __forceinline__ void load_row16_nt(const float* __restrict__ base,
                                              size_t row, float v[16]) {
  const f4* r = (const f4*)(base + row * 16);
#pragma unroll
  for (int q = 0; q < 4; ++q) {
    f4 t = __builtin_nontemporal_load(r + q);
    v[q * 4 + 0] = t[0]; v[q * 4 + 1] = t[1];
    v[q * 4 + 2] = t[2]; v[q * 4 + 3] = t[3];
  }
}

__device__ __forceinline__ h8 pack_h8(const float* v) {
  h8 o;
#pragma unroll
  for (int i = 0; i < 8; ++i) o[i] = (_Float16)v[i];
  return o;
}

__global__ __launch_bounds__(BLK)
void node_proj(const float* __restrict__ x, const float* __restrict__ W1,
               const float* __restrict__ W2, h8* __restrict__ p1h,
               h8* __restrict__ p2h, float* __restrict__ stats) {
  __shared__ __align__(16) float sW1[256];
  __shared__ __align__(16) float sW2[256];
  // fold the stats-zeroing into this kernel (completes before edge_pass1 starts)
  if (blockIdx.x == 0 && threadIdx.x < 32) stats[threadIdx.x] = 0.f;
  for (int i = threadIdx.x; i < 256; i += BLK) { sW1[i] = W1[i]; sW2[i] = W2[i]; }
  __syncthreads();
  int n = blockIdx.x * BLK + threadIdx.x;
  if (n >= NN) return;
  float xv[16];
  load_row16(x, (size_t)n, xv);
  float y1[16], y2[16];
#pragma unroll
  for (int j = 0; j < 16; ++j) { y1[j] = 0.f; y2[j] = 0.f; }
  matvec16_acc(sW1, xv, y1);
  matvec16_acc(sW2, xv, y2);
  // regular (cached) stores: pass1 reads these from L2 immediately after
  p1h[(size_t)n * 2 + 0] = pack_h8(y1);
  p1h[(size_t)n * 2 + 1] = pack_h8(y1 + 8);
  p2h[(size_t)n * 2 + 0] = pack_h8(y2);
  p2h[(size_t)n * 2 + 1] = pack_h8(y2 + 8);
}

// Pass 1: compute e = ea@W0.T + p1[s] + p2[d]; accumulate per-channel sum/sumsq;
// stash e (fp16 in ws if EH, else fp32 into out) so pass 2 never gathers.
// TABS=false fallback recomputes node projections from x (no ws tables).
template <bool TABS, bool EH>
__global__ __launch_bounds__(BLK, 4)   // cap VGPR at 128 -> 4 waves/SIMD
void edge_pass1(const float* __restrict__ ea, const int* __restrict__ ei,
                const float* __restrict__ xO, const h8* __restrict__ p1h,
                const h8* __restrict__ p2h, const float* __restrict__ W0g,
                const float* __restrict__ W1g, const float* __restrict__ W2g,
                float* __restrict__ stats, _Float16* __restrict__ eh,
                float* __restrict__ out) {
  __shared__ __align__(16) float sW0[256];
  __shared__ __align__(16) float sW1[256];
  __shared__ __align__(16) float sW2[256];
  __shared__ float red[4][32];
  for (int i = threadIdx.x; i < 256; i += BLK) {
    sW0[i] = W0g[i];
    if (!TABS) { sW1[i] = W1g[i]; sW2[i] = W2g[i]; }
  }
  __syncthreads();

  float sum[16], ssq[16];
#pragma unroll
  for (int j = 0; j < 16; ++j) { sum[j] = 0.f; ssq[j] = 0.f; }

  const int total = gridDim.x * BLK;
  int e = blockIdx.x * BLK + threadIdx.x;
  // software-pipelined index loads: (s,d) for the current edge are loaded one
  // iteration ahead so the gathers can issue immediately at loop top.
  int s = 0, d = 0;
  if (e < NE) {
    s = __builtin_nontemporal_load(ei + e);
    d = __builtin_nontemporal_load(ei + NE + e);
  }
  for (; e < NE; e += total) {
    int en = e + total;
    int sn = 0, dn = 0;
    if (en < NE) {
      sn = __builtin_nontemporal_load(ei + en);
      dn = __builtin_nontemporal_load(ei + NE + en);
    }
    float eav[16];
    float ev[16];
    if (TABS) {
      // gathers: regular loads — we WANT these cached in L2
      h8 a0 = p1h[(size_t)s * 2 + 0];
      h8 a1 = p1h[(size_t)s * 2 + 1];
      h8 b0 = p2h[(size_t)d * 2 + 0];
      h8 b1 = p2h[(size_t)d * 2 + 1];
      load_row16_nt(ea, (size_t)e, eav);
#pragma unroll
      for (int j = 0; j < 8; ++j) {
        ev[j]     = (float)a0[j] + (float)b0[j];
        ev[8 + j] = (float)a1[j] + (float)b1[j];
      }
      matvec16_acc(sW0, eav, ev);
    } else {
      float xs[16], xd[16];
      load_row16(xO, (size_t)s, xs);
      load_row16(xO, (size_t)d, xd);
      load_row16_nt(ea, (size_t)e, eav);
#pragma unroll
      for (int j = 0; j < 16; ++j) ev[j] = 0.f;
      matvec16_acc(sW0, eav, ev);
      matvec16_acc(sW1, xs, ev);
      matvec16_acc(sW2, xd, ev);
    }
#pragma unroll
    for (int j = 0; j < 16; ++j) {
      sum[j] += ev[j];
      ssq[j] = fmaf(ev[j], ev[j], ssq[j]);
    }
    if (EH) {
      h8* ep = (h8*)(eh + (size_t)e * 16);
      __builtin_nontemporal_store(pack_h8(ev), ep);
      __builtin_nontemporal_store(pack_h8(ev + 8), ep + 1);
    } else {
      f4* orow = (f4*)(out + (size_t)e * 16);
#pragma unroll
      for (int q = 0; q < 4; ++q) {
        f4 o;
        o[0] = ev[q * 4 + 0]; o[1] = ev[q * 4 + 1];
        o[2] = ev[q * 4 + 2]; o[3] = ev[q * 4 + 3];
        __builtin_nontemporal_store(o, orow + q);
      }
    }
    s = sn; d = dn;
  }

#pragma unroll
  for (int off = 32; off > 0; off >>= 1) {
#pragma unroll
    for (int j = 0; j < 16; ++j) {
      sum[j] += __shfl_down(sum[j], off);
      ssq[j] += __shfl_down(ssq[j], off);
    }
  }
  int wid = threadIdx.x >> 6;
  int lane = threadIdx.x & 63;
  if (lane == 0) {
#pragma unroll
    for (int j = 0; j < 16; ++j) {
      red[wid][j] = sum[j];
      red[wid][16 + j] = ssq[j];
    }
  }
  __syncthreads();
  if (threadIdx.x < 32) {
    float v = red[0][threadIdx.x] + red[1][threadIdx.x] +
              red[2][threadIdx.x] + red[3][threadIdx.x];
    atomicAdd(stats + threadIdx.x, v);
  }
}

// Pass 2: pure coalesced streaming — no gathers, no matvec.
// finalize is fused: each block derives scale/shift from stats (written by
// pass1's device-scope atomics; kernel boundary guarantees visibility).
// Flat float4-granular mapping: i in [0, NE*4); q = i&3 is constant per thread
// (stride is a multiple of 4), so scale/shift live in 8 registers.
template <bool EH>
__global__ __launch_bounds__(BLK, 8)
void edge_pass2(const float* __restrict__ ea, const _Float16* __restrict__ eh,
                const float* __restrict__ stats, const float* __restrict__ gamma,
                const float* __restrict__ beta, float* __restrict__ out) {
  __shared__ float sSS[32];
  if (threadIdx.x < 16) {
    int j = threadIdx.x;
    const float inv_n = 1.0f / (float)NE;
    float mean = stats[j] * inv_n;
    float var = fmaf(-mean, mean, stats[16 + j] * inv_n);
    float sc = gamma[j] / sqrtf(var + 1e-5f);
    sSS[j] = sc;
    sSS[16 + j] = fmaf(-mean, sc, beta[j]);
  }
  __syncthreads();
  const int totalv = NE * 4;
  const int stride = gridDim.x * BLK;
  int i0 = blockIdx.x * BLK + threadIdx.x;
  int c = (i0 & 3) * 4;
  float sc0 = sSS[c + 0], sc1 = sSS[c + 1], sc2 = sSS[c + 2], sc3 = sSS[c + 3];
  float sh0 = sSS[16 + c + 0], sh1 = sSS[16 + c + 1];
  float sh2 = sSS[16 + c + 2], sh3 = sSS[16 + c + 3];
  for (int i = i0; i < totalv; i += stride) {
    f4 av = __builtin_nontemporal_load((const f4*)ea + i);
    f4 evv;
    if (EH) {
      h4 hv = __builtin_nontemporal_load((const h4*)eh + i);
      evv[0] = (float)hv[0]; evv[1] = (float)hv[1];
      evv[2] = (float)hv[2]; evv[3] = (float)hv[3];
    } else {
      evv = __builtin_nontemporal_load((const f4*)out + i);
    }
    f4 o;
    o[0] = av[0] + fmaxf(0.f, fmaf(evv[0], sc0, sh0));
    o[1] = av[1] + fmaxf(0.f, fmaf(evv[1], sc1, sh1));
    o[2] = av[2] + fmaxf(0.f, fmaf(evv[2], sc2, sh2));
    o[3] = av[3] + fmaxf(0.f, fmaf(evv[3], sc3, sh3));
    __builtin_nontemporal_store(o, (f4*)out + i);
  }
}

extern "C" void kernel_launch(void* const* d_in, const int* in_sizes, int n_in,
                              void* d_out, int out_size, void* d_ws, size_t ws_size,
                              hipStream_t stream) {
  const float* x     = (const float*)d_in[0];
  const int*   ei    = (const int*)d_in[1];
  const float* ea    = (const float*)d_in[2];
  const float* W0    = (const float*)d_in[3];
  const float* W1    = (const float*)d_in[5];
  const float* W2    = (const float*)d_in[7];
  const float* gamma = (const float*)d_in[9];
  const float* beta  = (const float*)d_in[10];
  float* out = (float*)d_out;

  float* stats = (float*)d_ws;  // 32 floats @ byte 0
  h8* p1h = (h8*)((char*)d_ws + 1024);
  h8* p2h = p1h + (size_t)NN * 2;
  _Float16* eh = (_Float16*)(p2h + (size_t)NN * 2);

  size_t need_tabs = 1024 + (size_t)NN * 64;              // ~6.4 MB
  size_t need_eh   = need_tabs + (size_t)NE * 32;         // ~108.8 MB
  bool has_tabs = ws_size >= need_tabs;
  bool has_eh   = ws_size >= need_eh;

  if (has_tabs) {
    node_proj<<<(NN + BLK - 1) / BLK, BLK, 0, stream>>>(x, W1, W2, p1h, p2h, stats);
    if (has_eh)
      edge_pass1<true, true><<<GRID_EDGE, BLK, 0, stream>>>(
          ea, ei, x, p1h, p2h, W0, W1, W2, stats, eh, out);
    else
      edge_pass1<true, false><<<GRID_EDGE, BLK, 0, stream>>>(
          ea, ei, x, p1h, p2h, W0, W1, W2, stats, eh, out);
  } else {
    hipMemsetAsync(stats, 0, 32 * sizeof(float), stream);
    edge_pass1<false, false><<<GRID_EDGE, BLK, 0, stream>>>(
        ea, ei, x, p1h, p2h, W0, W1, W2, stats, eh, out);
  }

  if (has_eh)
    edge_pass2<true><<<GRID_EDGE, BLK, 0, stream>>>(ea, eh, stats, gamma, beta, out);
  else
    edge_pass2<false><<<GRID_EDGE, BLK, 0, stream>>>(ea, eh, stats, gamma, beta, out);
}

// Round 3
// 507.577 us; speedup vs baseline: 2.3351x; 2.3351x over previous
//
#include <hip/hip_runtime.h>
#include <math.h>

#define NN 100000
#define NE 3200000

constexpr int BLK = 256;
constexpr int GRID_E1 = 4096;   // fast pass1
constexpr int GRID_E2 = 2048;   // slow pass1 / pass2

typedef float f4 __attribute__((ext_vector_type(4)));
typedef _Float16 h4 __attribute__((ext_vector_type(4)));
typedef _Float16 h8 __attribute__((ext_vector_type(8)));

// ws layout (bytes):
//   [0,128)        stats: sum[16], sumsq[16]   (zeroed by node_proj block 0)
//   [1024, +3.2MB) p1h : NN rows x 16 half (32B/row)
//   [...,  +3.2MB) p2h
//   [..., +102.4MB) eh : NE rows x 16 half    (optional, if ws is big enough)

__device__ __forceinline__ void matvec16_acc(const float* __restrict__ sW,
                                             const float v[16], float acc[16]) {
#pragma unroll
  for (int j = 0; j < 16; ++j) {
    float a = acc[j];
#pragma unroll
    for (int q = 0; q < 4; ++q) {
      float4 w = ((const float4*)(sW + j * 16))[q];
      a = fmaf(v[q * 4 + 0], w.x, a);
      a = fmaf(v[q * 4 + 1], w.y, a);
      a = fmaf(v[q * 4 + 2], w.z, a);
      a = fmaf(v[q * 4 + 3], w.w, a);
    }
    acc[j] = a;
  }
}

__device__ __forceinline__ void load_row16(const float* __restrict__ base,
                                           size_t row, float v[16]) {
  const f4* r = (const f4*)(base + row * 16);
#pragma unroll
  for (int q = 0; q < 4; ++q) {
    f4 t = r[q];
    v[q * 4 + 0] = t[0]; v[q * 4 + 1] = t[1];
    v[q * 4 + 2] = t[2]; v[q * 4 + 3] = t[3];
  }
}

__device__ __forceinline__ void load_row16_nt(const float* __restrict__ base,
                                              size_t row, float v[16]) {
  const f4* r = (const f4*)(base + row * 16);
#pragma unroll
  for (int q = 0; q < 4; ++q) {
    f4 t = __builtin_nontemporal_load(r + q);
    v[q * 4 + 0] = t[0]; v[q * 4 + 1] = t[1];
    v[q * 4 + 2] = t[2]; v[q * 4 + 3] = t[3];
  }
}

__device__ __forceinline__ h8 pack_h8(const float* v) {
  h8 o;
#pragma unroll
  for (int i = 0; i < 8; ++i) o[i] = (_Float16)v[i];
  return o;
}

__global__ __launch_bounds__(BLK)
void node_proj(const float* __restrict__ x, const float* __restrict__ W1,
               const float* __restrict__ W2, h8* __restrict__ p1h,
               h8* __restrict__ p2h, float* __restrict__ stats) {
  __shared__ __align__(16) float sW1[256];
  __shared__ __align__(16) float sW2[256];
  if (blockIdx.x == 0 && threadIdx.x < 32) stats[threadIdx.x] = 0.f;
  for (int i = threadIdx.x; i < 256; i += BLK) { sW1[i] = W1[i]; sW2[i] = W2[i]; }
  __syncthreads();
  int n = blockIdx.x * BLK + threadIdx.x;
  if (n >= NN) return;
  float xv[16];
  load_row16(x, (size_t)n, xv);
  float y1[16], y2[16];
#pragma unroll
  for (int j = 0; j < 16; ++j) { y1[j] = 0.f; y2[j] = 0.f; }
  matvec16_acc(sW1, xv, y1);
  matvec16_acc(sW2, xv, y2);
  p1h[(size_t)n * 2 + 0] = pack_h8(y1);
  p1h[(size_t)n * 2 + 1] = pack_h8(y1 + 8);
  p2h[(size_t)n * 2 + 0] = pack_h8(y2);
  p2h[(size_t)n * 2 + 1] = pack_h8(y2 + 8);
}

// Fast pass 1: lane-pair decomposition. Lane r=tid&1 owns channels [8r,8r+8)
// of edge e=tid>>1. Per lane: 1x16B gather per table, 32B coalesced ea half,
// 8 shfl_xor for the other ea half. ~half the register state of the full-row
// version -> high occupancy WITHOUT forced launch bounds (round-2 lesson:
// never cap VGPR below the live set; it spills 2+ GB to scratch).
__global__ __launch_bounds__(BLK)
void edge_pass1_fast(const float* __restrict__ ea, const int* __restrict__ ei,
                     const h8* __restrict__ p1h, const h8* __restrict__ p2h,
                     const float* __restrict__ W0g, float* __restrict__ stats,
                     _Float16* __restrict__ eh) {
  __shared__ __align__(16) float sW0[256];
  __shared__ float red[4][32];
  for (int i = threadIdx.x; i < 256; i += BLK) sW0[i] = W0g[i];
  __syncthreads();

  float sum[8], ssq[8];
#pragma unroll
  for (int j = 0; j < 8; ++j) { sum[j] = 0.f; ssq[j] = 0.f; }

  const int tid = blockIdx.x * BLK + threadIdx.x;
  const int r = tid & 1;                     // channel half
  const int stride = (GRID_E1 * BLK) >> 1;   // edges per sweep
  int e = tid >> 1;

  int s = 0, d = 0;
  if (e < NE) {
    s = __builtin_nontemporal_load(ei + e);
    d = __builtin_nontemporal_load(ei + NE + e);
  }
  for (; e < NE; e += stride) {
    int en = e + stride;
    int sn = 0, dn = 0;
    if (en < NE) {
      sn = __builtin_nontemporal_load(ei + en);
      dn = __builtin_nontemporal_load(ei + NE + en);
    }
    // own contiguous 32B half of the ea row (perfectly coalesced across wave)
    const f4* ear = (const f4*)(ea + (size_t)e * 16 + r * 8);
    f4 a0 = __builtin_nontemporal_load(ear + 0);
    f4 a1 = __builtin_nontemporal_load(ear + 1);
    float own[8] = {a0[0], a0[1], a0[2], a0[3], a1[0], a1[1], a1[2], a1[3]};
    float oth[8];
#pragma unroll
    for (int k = 0; k < 8; ++k) oth[k] = __shfl_xor(own[k], 1);
    // gathers: one 16B request per table per lane (cached in L2 on purpose)
    h8 g1 = p1h[(size_t)s * 2 + r];
    h8 g2 = p2h[(size_t)d * 2 + r];
    float ev[8];
#pragma unroll
    for (int j = 0; j < 8; ++j) ev[j] = (float)g1[j] + (float)g2[j];
    // ev[j] += sum_k eav[k] * W0[8r+j][k]; select W halves by pointer, not data:
    // own holds channels [8r,8r+8) -> multiplies W columns [8r,..); oth the rest.
    const float* wbase = sW0 + r * 128;  // rows 8r..8r+7
#pragma unroll
    for (int j = 0; j < 8; ++j) {
      const float* wrow = wbase + j * 16;
      const f4* wA = (const f4*)(wrow + r * 8);        // x own
      const f4* wB = (const f4*)(wrow + (r ^ 1) * 8);  // x oth
      float acc = ev[j];
#pragma unroll
      for (int q = 0; q < 2; ++q) {
        f4 w = wA[q];
        acc = fmaf(own[4 * q + 0], w[0], acc);
        acc = fmaf(own[4 * q + 1], w[1], acc);
        acc = fmaf(own[4 * q + 2], w[2], acc);
        acc = fmaf(own[4 * q + 3], w[3], acc);
      }
#pragma unroll
      for (int q = 0; q < 2; ++q) {
        f4 w = wB[q];
        acc = fmaf(oth[4 * q + 0], w[0], acc);
        acc = fmaf(oth[4 * q + 1], w[1], acc);
        acc = fmaf(oth[4 * q + 2], w[2], acc);
        acc = fmaf(oth[4 * q + 3], w[3], acc);
      }
      ev[j] = acc;
    }
#pragma unroll
    for (int j = 0; j < 8; ++j) {
      sum[j] += ev[j];
      ssq[j] = fmaf(ev[j], ev[j], ssq[j]);
    }
    h8* ep = (h8*)(eh + (size_t)e * 16 + r * 8);
    __builtin_nontemporal_store(pack_h8(ev), ep);
    s = sn; d = dn;
  }

  // even offsets only: parity (=r) is preserved; lane0 ends with ch0-7 totals,
  // lane1 with ch8-15 totals.
#pragma unroll
  for (int off = 32; off >= 2; off >>= 1) {
#pragma unroll
    for (int j = 0; j < 8; ++j) {
      sum[j] += __shfl_down(sum[j], off);
      ssq[j] += __shfl_down(ssq[j], off);
    }
  }
  int wid = threadIdx.x >> 6;
  int lane = threadIdx.x & 63;
  if (lane < 2) {
#pragma unroll
    for (int j = 0; j < 8; ++j) {
      red[wid][lane * 8 + j] = sum[j];
      red[wid][16 + lane * 8 + j] = ssq[j];
    }
  }
  __syncthreads();
  if (threadIdx.x < 32) {
    float v = red[0][threadIdx.x] + red[1][threadIdx.x] +
              red[2][threadIdx.x] + red[3][threadIdx.x];
    atomicAdd(stats + threadIdx.x, v);
  }
}

// Slow/fallback pass 1 (full-row per thread) for degraded ws cases.
template <bool TABS, bool EH>
__global__ __launch_bounds__(BLK)
void edge_pass1(const float* __restrict__ ea, const int* __restrict__ ei,
                const float* __restrict__ xO, const h8* __restrict__ p1h,
                const h8* __restrict__ p2h, const float* __restrict__ W0g,
                const float* __restrict__ W1g, const float* __restrict__ W2g,
                float* __restrict__ stats, _Float16* __restrict__ eh,
                float* __restrict__ out) {
  __shared__ __align__(16) float sW0[256];
  __shared__ __align__(16) float sW1[256];
  __shared__ __align__(16) float sW2[256];
  __shared__ float red[4][32];
  for (int i = threadIdx.x; i < 256; i += BLK) {
    sW0[i] = W0g[i];
    if (!TABS) { sW1[i] = W1g[i]; sW2[i] = W2g[i]; }
  }
  __syncthreads();

  float sum[16], ssq[16];
#pragma unroll
  for (int j = 0; j < 16; ++j) { sum[j] = 0.f; ssq[j] = 0.f; }

  const int total = gridDim.x * BLK;
  for (int e = blockIdx.x * BLK + threadIdx.x; e < NE; e += total) {
    int s = __builtin_nontemporal_load(ei + e);
    int d = __builtin_nontemporal_load(ei + NE + e);
    float eav[16];
    load_row16_nt(ea, (size_t)e, eav);
    float ev[16];
    if (TABS) {
      h8 a0 = p1h[(size_t)s * 2 + 0];
      h8 a1 = p1h[(size_t)s * 2 + 1];
      h8 b0 = p2h[(size_t)d * 2 + 0];
      h8 b1 = p2h[(size_t)d * 2 + 1];
#pragma unroll
      for (int j = 0; j < 8; ++j) {
        ev[j]     = (float)a0[j] + (float)b0[j];
        ev[8 + j] = (float)a1[j] + (float)b1[j];
      }
      matvec16_acc(sW0, eav, ev);
    } else {
      float xs[16], xd[16];
      load_row16(xO, (size_t)s, xs);
      load_row16(xO, (size_t)d, xd);
#pragma unroll
      for (int j = 0; j < 16; ++j) ev[j] = 0.f;
      matvec16_acc(sW0, eav, ev);
      matvec16_acc(sW1, xs, ev);
      matvec16_acc(sW2, xd, ev);
    }
#pragma unroll
    for (int j = 0; j < 16; ++j) {
      sum[j] += ev[j];
      ssq[j] = fmaf(ev[j], ev[j], ssq[j]);
    }
    if (EH) {
      h8* ep = (h8*)(eh + (size_t)e * 16);
      __builtin_nontemporal_store(pack_h8(ev), ep);
      __builtin_nontemporal_store(pack_h8(ev + 8), ep + 1);
    } else {
      f4* orow = (f4*)(out + (size_t)e * 16);
#pragma unroll
      for (int q = 0; q < 4; ++q) {
        f4 o;
        o[0] = ev[q * 4 + 0]; o[1] = ev[q * 4 + 1];
        o[2] = ev[q * 4 + 2]; o[3] = ev[q * 4 + 3];
        __builtin_nontemporal_store(o, orow + q);
      }
    }
  }

#pragma unroll
  for (int off = 32; off > 0; off >>= 1) {
#pragma unroll
    for (int j = 0; j < 16; ++j) {
      sum[j] += __shfl_down(sum[j], off);
      ssq[j] += __shfl_down(ssq[j], off);
    }
  }
  int wid = threadIdx.x >> 6;
  int lane = threadIdx.x & 63;
  if (lane == 0) {
#pragma unroll
    for (int j = 0; j < 16; ++j) {
      red[wid][j] = sum[j];
      red[wid][16 + j] = ssq[j];
    }
  }
  __syncthreads();
  if (threadIdx.x < 32) {
    float v = red[0][threadIdx.x] + red[1][threadIdx.x] +
              red[2][threadIdx.x] + red[3][threadIdx.x];
    atomicAdd(stats + threadIdx.x, v);
  }
}

// Pass 2: pure coalesced streaming; finalize fused (scale/shift from stats).
template <bool EH>
__global__ __launch_bounds__(BLK, 8)
void edge_pass2(const float* __restrict__ ea, const _Float16* __restrict__ eh,
                const float* __restrict__ stats, const float* __restrict__ gamma,
                const float* __restrict__ beta, float* __restrict__ out) {
  __shared__ float sSS[32];
  if (threadIdx.x < 16) {
    int j = threadIdx.x;
    const float inv_n = 1.0f / (float)NE;
    float mean = stats[j] * inv_n;
    float var = fmaf(-mean, mean, stats[16 + j] * inv_n);
    float sc = gamma[j] / sqrtf(var + 1e-5f);
    sSS[j] = sc;
    sSS[16 + j] = fmaf(-mean, sc, beta[j]);
  }
  __syncthreads();
  const int totalv = NE * 4;
  const int stride = gridDim.x * BLK;
  int i0 = blockIdx.x * BLK + threadIdx.x;
  int c = (i0 & 3) * 4;
  float sc0 = sSS[c + 0], sc1 = sSS[c + 1], sc2 = sSS[c + 2], sc3 = sSS[c + 3];
  float sh0 = sSS[16 + c + 0], sh1 = sSS[16 + c + 1];
  float sh2 = sSS[16 + c + 2], sh3 = sSS[16 + c + 3];
  for (int i = i0; i < totalv; i += stride) {
    f4 av = __builtin_nontemporal_load((const f4*)ea + i);
    f4 evv;
    if (EH) {
      h4 hv = __builtin_nontemporal_load((const h4*)eh + i);
      evv[0] = (float)hv[0]; evv[1] = (float)hv[1];
      evv[2] = (float)hv[2]; evv[3] = (float)hv[3];
    } else {
      evv = __builtin_nontemporal_load((const f4*)out + i);
    }
    f4 o;
    o[0] = av[0] + fmaxf(0.f, fmaf(evv[0], sc0, sh0));
    o[1] = av[1] + fmaxf(0.f, fmaf(evv[1], sc1, sh1));
    o[2] = av[2] + fmaxf(0.f, fmaf(evv[2], sc2, sh2));
    o[3] = av[3] + fmaxf(0.f, fmaf(evv[3], sc3, sh3));
    __builtin_nontemporal_store(o, (f4*)out + i);
  }
}

extern "C" void kernel_launch(void* const* d_in, const int* in_sizes, int n_in,
                              void* d_out, int out_size, void* d_ws, size_t ws_size,
                              hipStream_t stream) {
  const float* x     = (const float*)d_in[0];
  const int*   ei    = (const int*)d_in[1];
  const float* ea    = (const float*)d_in[2];
  const float* W0    = (const float*)d_in[3];
  const float* W1    = (const float*)d_in[5];
  const float* W2    = (const float*)d_in[7];
  const float* gamma = (const float*)d_in[9];
  const float* beta  = (const float*)d_in[10];
  float* out = (float*)d_out;

  float* stats = (float*)d_ws;  // 32 floats @ byte 0
  h8* p1h = (h8*)((char*)d_ws + 1024);
  h8* p2h = p1h + (size_t)NN * 2;
  _Float16* eh = (_Float16*)(p2h + (size_t)NN * 2);

  size_t need_tabs = 1024 + (size_t)NN * 64;              // ~6.4 MB
  size_t need_eh   = need_tabs + (size_t)NE * 32;         // ~108.8 MB
  bool has_tabs = ws_size >= need_tabs;
  bool has_eh   = ws_size >= need_eh;

  if (has_tabs) {
    node_proj<<<(NN + BLK - 1) / BLK, BLK, 0, stream>>>(x, W1, W2, p1h, p2h, stats);
    if (has_eh)
      edge_pass1_fast<<<GRID_E1, BLK, 0, stream>>>(ea, ei, p1h, p2h, W0, stats, eh);
    else
      edge_pass1<true, false><<<GRID_E2, BLK, 0, stream>>>(
          ea, ei, x, p1h, p2h, W0, W1, W2, stats, eh, out);
  } else {
    hipMemsetAsync(stats, 0, 32 * sizeof(float), stream);
    edge_pass1<false, false><<<GRID_E2, BLK, 0, stream>>>(
        ea, ei, x, p1h, p2h, W0, W1, W2, stats, eh, out);
  }

  if (has_eh)
    edge_pass2<true><<<GRID_E2, BLK, 0, stream>>>(ea, eh, stats, gamma, beta, out);
  else
    edge_pass2<false><<<GRID_E2, BLK, 0, stream>>>(ea, eh, stats, gamma, beta, out);
}

// Round 4
// 498.564 us; speedup vs baseline: 2.3774x; 1.0181x over previous
//
#include <hip/hip_runtime.h>
#include <math.h>

#define NN 100000
#define NE 3200000

constexpr int BLK = 256;
constexpr int GRID_E1 = 2048;   // fast pass1 (persistent-ish, ~12 iters/thread)
constexpr int GRID_E2 = 2048;   // slow pass1 / pass2

typedef float f4 __attribute__((ext_vector_type(4)));
typedef _Float16 h4 __attribute__((ext_vector_type(4)));
typedef _Float16 h8 __attribute__((ext_vector_type(8)));

// ws layout (bytes):
//   [0,128)        stats: sum[16], sumsq[16]   (zeroed by node_proj block 0)
//   [1024, +3.2MB) p1h : NN rows x 16 half (32B/row)
//   [...,  +3.2MB) p2h
//   [..., +102.4MB) eh : NE rows x 16 half    (optional, if ws is big enough)

__device__ __forceinline__ void matvec16_acc(const float* __restrict__ sW,
                                             const float v[16], float acc[16]) {
#pragma unroll
  for (int j = 0; j < 16; ++j) {
    float a = acc[j];
#pragma unroll
    for (int q = 0; q < 4; ++q) {
      float4 w = ((const float4*)(sW + j * 16))[q];
      a = fmaf(v[q * 4 + 0], w.x, a);
      a = fmaf(v[q * 4 + 1], w.y, a);
      a = fmaf(v[q * 4 + 2], w.z, a);
      a = fmaf(v[q * 4 + 3], w.w, a);
    }
    acc[j] = a;
  }
}

__device__ __forceinline__ void load_row16(const float* __restrict__ base,
                                           size_t row, float v[16]) {
  const f4* r = (const f4*)(base + row * 16);
#pragma unroll
  for (int q = 0; q < 4; ++q) {
    f4 t = r[q];
    v[q * 4 + 0] = t[0]; v[q * 4 + 1] = t[1];
    v[q * 4 + 2] = t[2]; v[q * 4 + 3] = t[3];
  }
}

__device__ __forceinline__ void load_row16_nt(const float* __restrict__ base,
                                              size_t row, float v[16]) {
  const f4* r = (const f4*)(base + row * 16);
#pragma unroll
  for (int q = 0; q < 4; ++q) {
    f4 t = __builtin_nontemporal_load(r + q);
    v[q * 4 + 0] = t[0]; v[q * 4 + 1] = t[1];
    v[q * 4 + 2] = t[2]; v[q * 4 + 3] = t[3];
  }
}

__device__ __forceinline__ h8 pack_h8(const float* v) {
  h8 o;
#pragma unroll
  for (int i = 0; i < 8; ++i) o[i] = (_Float16)v[i];
  return o;
}

__global__ __launch_bounds__(BLK)
void node_proj(const float* __restrict__ x, const float* __restrict__ W1,
               const float* __restrict__ W2, h8* __restrict__ p1h,
               h8* __restrict__ p2h, float* __restrict__ stats) {
  __shared__ __align__(16) float sW1[256];
  __shared__ __align__(16) float sW2[256];
  if (blockIdx.x == 0 && threadIdx.x < 32) stats[threadIdx.x] = 0.f;
  for (int i = threadIdx.x; i < 256; i += BLK) { sW1[i] = W1[i]; sW2[i] = W2[i]; }
  __syncthreads();
  int n = blockIdx.x * BLK + threadIdx.x;
  if (n >= NN) return;
  float xv[16];
  load_row16(x, (size_t)n, xv);
  float y1[16], y2[16];
#pragma unroll
  for (int j = 0; j < 16; ++j) { y1[j] = 0.f; y2[j] = 0.f; }
  matvec16_acc(sW1, xv, y1);
  matvec16_acc(sW2, xv, y2);
  p1h[(size_t)n * 2 + 0] = pack_h8(y1);
  p1h[(size_t)n * 2 + 1] = pack_h8(y1 + 8);
  p2h[(size_t)n * 2 + 0] = pack_h8(y2);
  p2h[(size_t)n * 2 + 1] = pack_h8(y2 + 8);
}

// Fast pass 1: lane-pair decomposition (lane r=tid&1 owns channels [8r,8r+8)
// of edge e=tid>>1) + full software pipeline:
//   indices prefetched 2 iterations ahead,
//   data (ea halves + both table gathers) prefetched 1 iteration ahead,
// so each iteration's ~90 VALU ops of compute hide the NEXT iteration's
// memory latency instead of stalling on its own loads.
// Round-2 lesson: never force launch bounds below the live set (2+GB spills).
__global__ __launch_bounds__(BLK)
void edge_pass1_fast(const float* __restrict__ ea, const int* __restrict__ ei,
                     const h8* __restrict__ p1h, const h8* __restrict__ p2h,
                     const float* __restrict__ W0g, float* __restrict__ stats,
                     _Float16* __restrict__ eh) {
  __shared__ __align__(16) float sW0[256];
  __shared__ float red[4][32];
  for (int i = threadIdx.x; i < 256; i += BLK) sW0[i] = W0g[i];
  __syncthreads();

  float sum[8], ssq[8];
#pragma unroll
  for (int j = 0; j < 8; ++j) { sum[j] = 0.f; ssq[j] = 0.f; }

  const int tid = blockIdx.x * BLK + threadIdx.x;
  const int r = tid & 1;                     // channel half
  const int S = (GRID_E1 * BLK) >> 1;        // edges per sweep
  int e = tid >> 1;

  // ---- pipeline prologue ----
  int s1 = 0, d1 = 0;   // indices for current edge e (needed immediately)
  int s2 = 0, d2 = 0;   // indices for e+S (gathers issued next iteration)
  f4 a0c = {}, a1c = {};
  h8 g1c = {}, g2c = {};
  if (e < NE) {
    s1 = ei[e];
    d1 = ei[NE + e];
  }
  if (e + S < NE) {
    s2 = __builtin_nontemporal_load(ei + e + S);
    d2 = __builtin_nontemporal_load(ei + NE + e + S);
  }
  if (e < NE) {
    const f4* ear = (const f4*)(ea + (size_t)e * 16 + r * 8);
    a0c = __builtin_nontemporal_load(ear + 0);
    a1c = __builtin_nontemporal_load(ear + 1);
    g1c = p1h[(size_t)s1 * 2 + r];
    g2c = p2h[(size_t)d1 * 2 + r];
  }

  f4 a0n = {}, a1n = {};
  h8 g1n = {}, g2n = {};
  for (; e < NE; e += S) {
    const int en = e + S;
    const int enn = en + S;
    // issue NEXT iteration's data loads first (latency hidden under compute)
    if (en < NE) {
      const f4* earn = (const f4*)(ea + (size_t)en * 16 + r * 8);
      a0n = __builtin_nontemporal_load(earn + 0);
      a1n = __builtin_nontemporal_load(earn + 1);
      g1n = p1h[(size_t)s2 * 2 + r];
      g2n = p2h[(size_t)d2 * 2 + r];
    }
    int s3 = 0, d3 = 0;
    if (enn < NE) {
      s3 = __builtin_nontemporal_load(ei + enn);
      d3 = __builtin_nontemporal_load(ei + NE + enn);
    }

    // ---- compute with CURRENT data ----
    float own[8] = {a0c[0], a0c[1], a0c[2], a0c[3],
                    a1c[0], a1c[1], a1c[2], a1c[3]};
    float oth[8];
#pragma unroll
    for (int k = 0; k < 8; ++k) oth[k] = __shfl_xor(own[k], 1);
    float ev[8];
#pragma unroll
    for (int j = 0; j < 8; ++j) ev[j] = (float)g1c[j] + (float)g2c[j];
    // ev[j] += sum_k eav[k] * W0[8r+j][k]; W halves selected by pointer.
    const float* wbase = sW0 + r * 128;  // rows 8r..8r+7
#pragma unroll
    for (int j = 0; j < 8; ++j) {
      const float* wrow = wbase + j * 16;
      const f4* wA = (const f4*)(wrow + r * 8);        // x own
      const f4* wB = (const f4*)(wrow + (r ^ 1) * 8);  // x oth
      float acc = ev[j];
#pragma unroll
      for (int q = 0; q < 2; ++q) {
        f4 w = wA[q];
        acc = fmaf(own[4 * q + 0], w[0], acc);
        acc = fmaf(own[4 * q + 1], w[1], acc);
        acc = fmaf(own[4 * q + 2], w[2], acc);
        acc = fmaf(own[4 * q + 3], w[3], acc);
      }
#pragma unroll
      for (int q = 0; q < 2; ++q) {
        f4 w = wB[q];
        acc = fmaf(oth[4 * q + 0], w[0], acc);
        acc = fmaf(oth[4 * q + 1], w[1], acc);
        acc = fmaf(oth[4 * q + 2], w[2], acc);
        acc = fmaf(oth[4 * q + 3], w[3], acc);
      }
      ev[j] = acc;
    }
#pragma unroll
    for (int j = 0; j < 8; ++j) {
      sum[j] += ev[j];
      ssq[j] = fmaf(ev[j], ev[j], ssq[j]);
    }
    h8* ep = (h8*)(eh + (size_t)e * 16 + r * 8);
    __builtin_nontemporal_store(pack_h8(ev), ep);

    // ---- rotate pipeline ----
    a0c = a0n; a1c = a1n; g1c = g1n; g2c = g2n;
    s2 = s3; d2 = d3;
  }

  // parity-preserving reduction: lane0 ends with ch0-7, lane1 with ch8-15.
#pragma unroll
  for (int off = 32; off >= 2; off >>= 1) {
#pragma unroll
    for (int j = 0; j < 8; ++j) {
      sum[j] += __shfl_down(sum[j], off);
      ssq[j] += __shfl_down(ssq[j], off);
    }
  }
  int wid = threadIdx.x >> 6;
  int lane = threadIdx.x & 63;
  if (lane < 2) {
#pragma unroll
    for (int j = 0; j < 8; ++j) {
      red[wid][lane * 8 + j] = sum[j];
      red[wid][16 + lane * 8 + j] = ssq[j];
    }
  }
  __syncthreads();
  if (threadIdx.x < 32) {
    float v = red[0][threadIdx.x] + red[1][threadIdx.x] +
              red[2][threadIdx.x] + red[3][threadIdx.x];
    atomicAdd(stats + threadIdx.x, v);
  }
}

// Slow/fallback pass 1 (full-row per thread) for degraded ws cases.
template <bool TABS, bool EH>
__global__ __launch_bounds__(BLK)
void edge_pass1(const float* __restrict__ ea, const int* __restrict__ ei,
                const float* __restrict__ xO, const h8* __restrict__ p1h,
                const h8* __restrict__ p2h, const float* __restrict__ W0g,
                const float* __restrict__ W1g, const float* __restrict__ W2g,
                float* __restrict__ stats, _Float16* __restrict__ eh,
                float* __restrict__ out) {
  __shared__ __align__(16) float sW0[256];
  __shared__ __align__(16) float sW1[256];
  __shared__ __align__(16) float sW2[256];
  __shared__ float red[4][32];
  for (int i = threadIdx.x; i < 256; i += BLK) {
    sW0[i] = W0g[i];
    if (!TABS) { sW1[i] = W1g[i]; sW2[i] = W2g[i]; }
  }
  __syncthreads();

  float sum[16], ssq[16];
#pragma unroll
  for (int j = 0; j < 16; ++j) { sum[j] = 0.f; ssq[j] = 0.f; }

  const int total = gridDim.x * BLK;
  for (int e = blockIdx.x * BLK + threadIdx.x; e < NE; e += total) {
    int s = __builtin_nontemporal_load(ei + e);
    int d = __builtin_nontemporal_load(ei + NE + e);
    float eav[16];
    load_row16_nt(ea, (size_t)e, eav);
    float ev[16];
    if (TABS) {
      h8 a0 = p1h[(size_t)s * 2 + 0];
      h8 a1 = p1h[(size_t)s * 2 + 1];
      h8 b0 = p2h[(size_t)d * 2 + 0];
      h8 b1 = p2h[(size_t)d * 2 + 1];
#pragma unroll
      for (int j = 0; j < 8; ++j) {
        ev[j]     = (float)a0[j] + (float)b0[j];
        ev[8 + j] = (float)a1[j] + (float)b1[j];
      }
      matvec16_acc(sW0, eav, ev);
    } else {
      float xs[16], xd[16];
      load_row16(xO, (size_t)s, xs);
      load_row16(xO, (size_t)d, xd);
#pragma unroll
      for (int j = 0; j < 16; ++j) ev[j] = 0.f;
      matvec16_acc(sW0, eav, ev);
      matvec16_acc(sW1, xs, ev);
      matvec16_acc(sW2, xd, ev);
    }
#pragma unroll
    for (int j = 0; j < 16; ++j) {
      sum[j] += ev[j];
      ssq[j] = fmaf(ev[j], ev[j], ssq[j]);
    }
    if (EH) {
      h8* ep = (h8*)(eh + (size_t)e * 16);
      __builtin_nontemporal_store(pack_h8(ev), ep);
      __builtin_nontemporal_store(pack_h8(ev + 8), ep + 1);
    } else {
      f4* orow = (f4*)(out + (size_t)e * 16);
#pragma unroll
      for (int q = 0; q < 4; ++q) {
        f4 o;
        o[0] = ev[q * 4 + 0]; o[1] = ev[q * 4 + 1];
        o[2] = ev[q * 4 + 2]; o[3] = ev[q * 4 + 3];
        __builtin_nontemporal_store(o, orow + q);
      }
    }
  }

#pragma unroll
  for (int off = 32; off > 0; off >>= 1) {
#pragma unroll
    for (int j = 0; j < 16; ++j) {
      sum[j] += __shfl_down(sum[j], off);
      ssq[j] += __shfl_down(ssq[j], off);
    }
  }
  int wid = threadIdx.x >> 6;
  int lane = threadIdx.x & 63;
  if (lane == 0) {
#pragma unroll
    for (int j = 0; j < 16; ++j) {
      red[wid][j] = sum[j];
      red[wid][16 + j] = ssq[j];
    }
  }
  __syncthreads();
  if (threadIdx.x < 32) {
    float v = red[0][threadIdx.x] + red[1][threadIdx.x] +
              red[2][threadIdx.x] + red[3][threadIdx.x];
    atomicAdd(stats + threadIdx.x, v);
  }
}

// Pass 2: pure coalesced streaming; finalize fused (scale/shift from stats).
template <bool EH>
__global__ __launch_bounds__(BLK, 8)
void edge_pass2(const float* __restrict__ ea, const _Float16* __restrict__ eh,
                const float* __restrict__ stats, const float* __restrict__ gamma,
                const float* __restrict__ beta, float* __restrict__ out) {
  __shared__ float sSS[32];
  if (threadIdx.x < 16) {
    int j = threadIdx.x;
    const float inv_n = 1.0f / (float)NE;
    float mean = stats[j] * inv_n;
    float var = fmaf(-mean, mean, stats[16 + j] * inv_n);
    float sc = gamma[j] / sqrtf(var + 1e-5f);
    sSS[j] = sc;
    sSS[16 + j] = fmaf(-mean, sc, beta[j]);
  }
  __syncthreads();
  const int totalv = NE * 4;
  const int stride = gridDim.x * BLK;
  int i0 = blockIdx.x * BLK + threadIdx.x;
  int c = (i0 & 3) * 4;
  float sc0 = sSS[c + 0], sc1 = sSS[c + 1], sc2 = sSS[c + 2], sc3 = sSS[c + 3];
  float sh0 = sSS[16 + c + 0], sh1 = sSS[16 + c + 1];
  float sh2 = sSS[16 + c + 2], sh3 = sSS[16 + c + 3];
  for (int i = i0; i < totalv; i += stride) {
    f4 av = __builtin_nontemporal_load((const f4*)ea + i);
    f4 evv;
    if (EH) {
      h4 hv = __builtin_nontemporal_load((const h4*)eh + i);
      evv[0] = (float)hv[0]; evv[1] = (float)hv[1];
      evv[2] = (float)hv[2]; evv[3] = (float)hv[3];
    } else {
      evv = __builtin_nontemporal_load((const f4*)out + i);
    }
    f4 o;
    o[0] = av[0] + fmaxf(0.f, fmaf(evv[0], sc0, sh0));
    o[1] = av[1] + fmaxf(0.f, fmaf(evv[1], sc1, sh1));
    o[2] = av[2] + fmaxf(0.f, fmaf(evv[2], sc2, sh2));
    o[3] = av[3] + fmaxf(0.f, fmaf(evv[3], sc3, sh3));
    __builtin_nontemporal_store(o, (f4*)out + i);
  }
}

extern "C" void kernel_launch(void* const* d_in, const int* in_sizes, int n_in,
                              void* d_out, int out_size, void* d_ws, size_t ws_size,
                              hipStream_t stream) {
  const float* x     = (const float*)d_in[0];
  const int*   ei    = (const int*)d_in[1];
  const float* ea    = (const float*)d_in[2];
  const float* W0    = (const float*)d_in[3];
  const float* W1    = (const float*)d_in[5];
  const float* W2    = (const float*)d_in[7];
  const float* gamma = (const float*)d_in[9];
  const float* beta  = (const float*)d_in[10];
  float* out = (float*)d_out;

  float* stats = (float*)d_ws;  // 32 floats @ byte 0
  h8* p1h = (h8*)((char*)d_ws + 1024);
  h8* p2h = p1h + (size_t)NN * 2;
  _Float16* eh = (_Float16*)(p2h + (size_t)NN * 2);

  size_t need_tabs = 1024 + (size_t)NN * 64;              // ~6.4 MB
  size_t need_eh   = need_tabs + (size_t)NE * 32;         // ~108.8 MB
  bool has_tabs = ws_size >= need_tabs;
  bool has_eh   = ws_size >= need_eh;

  if (has_tabs) {
    node_proj<<<(NN + BLK - 1) / BLK, BLK, 0, stream>>>(x, W1, W2, p1h, p2h, stats);
    if (has_eh)
      edge_pass1_fast<<<GRID_E1, BLK, 0, stream>>>(ea, ei, p1h, p2h, W0, stats, eh);
    else
      edge_pass1<true, false><<<GRID_E2, BLK, 0, stream>>>(
          ea, ei, x, p1h, p2h, W0, W1, W2, stats, eh, out);
  } else {
    hipMemsetAsync(stats, 0, 32 * sizeof(float), stream);
    edge_pass1<false, false><<<GRID_E2, BLK, 0, stream>>>(
        ea, ei, x, p1h, p2h, W0, W1, W2, stats, eh, out);
  }

  if (has_eh)
    edge_pass2<true><<<GRID_E2, BLK, 0, stream>>>(ea, eh, stats, gamma, beta, out);
  else
    edge_pass2<false><<<GRID_E2, BLK, 0, stream>>>(ea, eh, stats, gamma, beta, out);
}